// Round 1
// baseline (1020.952 us; speedup 1.0000x reference)
//
#include <hip/hip_runtime.h>

#define S_LEN 2304   // 48*48
#define K_DIM 512    // C
#define NHEAD 8
#define HDIM  64

// ---------------------------------------------------------------------------
// Generic projection GEMM: Y[b][m][n] = sum_k W[m][k] * X[b][k][n] + bias[m]
// W: [M][512] row-major, X: [B][512][2304], Y: [B][M][2304]
// 128x128 block tile, K-tile 16, 8x8 per-thread register tile, 256 threads.
// ---------------------------------------------------------------------------
__global__ __launch_bounds__(256) void gemm_proj(
    const float* __restrict__ W, const float* __restrict__ bias,
    const float* __restrict__ X, float* __restrict__ Y, int M)
{
    const int N = S_LEN, K = K_DIM;
    const int n0 = blockIdx.x * 128;
    const int m0 = blockIdx.y * 128;
    const int b  = blockIdx.z;

    __shared__ float As[16][132];   // [k][m]  (pad 132: f4-aligned rows, bank-spread)
    __shared__ float Bs[16][132];   // [k][n]

    const float* Xb = X + (size_t)b * K * N;
    float*       Yb = Y + (size_t)b * M * N;

    const int tid = threadIdx.x;
    const int tx  = tid & 15;   // n direction
    const int ty  = tid >> 4;   // m direction

    float acc[8][8];
#pragma unroll
    for (int i = 0; i < 8; i++)
#pragma unroll
        for (int j = 0; j < 8; j++) acc[i][j] = 0.f;

    for (int k0 = 0; k0 < K; k0 += 16) {
        // A tile: 128 rows x 16 k  -> 512 float4, 2 per thread
#pragma unroll
        for (int p = 0; p < 2; p++) {
            int idx = tid + p * 256;
            int m   = idx >> 2;
            int kq  = (idx & 3) << 2;
            float4 a = *(const float4*)(W + (size_t)(m0 + m) * K + k0 + kq);
            As[kq + 0][m] = a.x;
            As[kq + 1][m] = a.y;
            As[kq + 2][m] = a.z;
            As[kq + 3][m] = a.w;
        }
        // B tile: 16 k x 128 n -> 512 float4, 2 per thread (coalesced)
#pragma unroll
        for (int p = 0; p < 2; p++) {
            int idx = tid + p * 256;
            int kk  = idx >> 5;
            int nq  = (idx & 31) << 2;
            *(float4*)&Bs[kk][nq] =
                *(const float4*)(Xb + (size_t)(k0 + kk) * N + n0 + nq);
        }
        __syncthreads();

#pragma unroll
        for (int k = 0; k < 16; k++) {
            float a[8], bb[8];
            *(float4*)&a[0]  = *(float4*)&As[k][ty * 8];
            *(float4*)&a[4]  = *(float4*)&As[k][ty * 8 + 4];
            *(float4*)&bb[0] = *(float4*)&Bs[k][tx * 8];
            *(float4*)&bb[4] = *(float4*)&Bs[k][tx * 8 + 4];
#pragma unroll
            for (int i = 0; i < 8; i++)
#pragma unroll
                for (int j = 0; j < 8; j++)
                    acc[i][j] = fmaf(a[i], bb[j], acc[i][j]);
        }
        __syncthreads();
    }

#pragma unroll
    for (int i = 0; i < 8; i++) {
        int m = m0 + ty * 8 + i;
        float bv = bias[m];
        float4 o0, o1;
        o0.x = acc[i][0] + bv; o0.y = acc[i][1] + bv;
        o0.z = acc[i][2] + bv; o0.w = acc[i][3] + bv;
        o1.x = acc[i][4] + bv; o1.y = acc[i][5] + bv;
        o1.z = acc[i][6] + bv; o1.w = acc[i][7] + bv;
        float* yrow = Yb + (size_t)m * N + n0 + tx * 8;
        *(float4*)yrow       = o0;
        *(float4*)(yrow + 4) = o1;
    }
}

// ---------------------------------------------------------------------------
// Flash attention, fp32. qkv layout: [B][3*512][S] with q at rows h*64+d,
// k at 512+h*64+d, v at 1024+h*64+d. Output att: [B][512][S], c = h*64+d.
// One block = one (b, h, 64-query tile). 256 threads; thread (tx,ty) owns the
// 4x4 sub-tile s = ty*4+i, t/d = tx*4+j. Online softmax; K and V time-share
// one LDS buffer (static LDS 3*17408 = 52.2 KB < 64 KB limit).
// ---------------------------------------------------------------------------
__global__ __launch_bounds__(256) void attn_fwd(
    const float* __restrict__ qkv, float* __restrict__ out)
{
    const int s0 = blockIdx.x * 64;
    const int h  = blockIdx.y;
    const int b  = blockIdx.z;
    const size_t hb = ((size_t)b * 1536 + (size_t)h * HDIM) * S_LEN;
    const float* Q  = qkv + hb;
    const float* Kp = qkv + hb + (size_t)512  * S_LEN;
    const float* Vp = qkv + hb + (size_t)1024 * S_LEN;

    __shared__ float Qs[64][68];   // [d][s]
    __shared__ float KVs[64][68];  // K phase: [d][t];  V phase: [t][d]
    __shared__ float Ps[64][68];   // [s][t], reused as [d][s] for epilogue

    const int tid  = threadIdx.x;
    const int tx   = tid & 15;
    const int ty   = tid >> 4;
    const int ld_d = tid >> 2;          // 0..63 (row for loads)
    const int ld_q = (tid & 3) << 4;    // 0,16,32,48 (16-float chunk)

    // Load Q tile [d][s]
#pragma unroll
    for (int u = 0; u < 4; u++) {
        *(float4*)&Qs[ld_d][ld_q + u * 4] =
            *(const float4*)(Q + (size_t)ld_d * S_LEN + s0 + ld_q + u * 4);
    }

    float m_run[4], l_run[4], O[4][4];
#pragma unroll
    for (int i = 0; i < 4; i++) {
        m_run[i] = -1e30f;
        l_run[i] = 0.f;
#pragma unroll
        for (int j = 0; j < 4; j++) O[i][j] = 0.f;
    }

    for (int t0 = 0; t0 < S_LEN; t0 += 64) {
        __syncthreads();  // prev PV done with KVs/Ps (also fences Q load, iter 0)

        // Load K tile [d][t]
#pragma unroll
        for (int u = 0; u < 4; u++) {
            *(float4*)&KVs[ld_d][ld_q + u * 4] =
                *(const float4*)(Kp + (size_t)ld_d * S_LEN + t0 + ld_q + u * 4);
        }
        __syncthreads();

        // S = (Q^T K) * scale
        float sacc[4][4];
#pragma unroll
        for (int i = 0; i < 4; i++)
#pragma unroll
            for (int j = 0; j < 4; j++) sacc[i][j] = 0.f;

#pragma unroll 8
        for (int d = 0; d < 64; d++) {
            float qa[4], kb[4];
            *(float4*)qa = *(float4*)&Qs[d][ty * 4];
            *(float4*)kb = *(float4*)&KVs[d][tx * 4];
#pragma unroll
            for (int i = 0; i < 4; i++)
#pragma unroll
                for (int j = 0; j < 4; j++)
                    sacc[i][j] = fmaf(qa[i], kb[j], sacc[i][j]);
        }

        // Online softmax update (row stats across the 16-lane tx group)
#pragma unroll
        for (int i = 0; i < 4; i++) {
            float rmax = -1e30f;
#pragma unroll
            for (int j = 0; j < 4; j++) {
                sacc[i][j] *= 0.125f;  // 1/sqrt(64)
                rmax = fmaxf(rmax, sacc[i][j]);
            }
#pragma unroll
            for (int mm = 1; mm < 16; mm <<= 1)
                rmax = fmaxf(rmax, __shfl_xor(rmax, mm));
            float mnew = fmaxf(m_run[i], rmax);
            float sc   = __expf(m_run[i] - mnew);
            float p[4], rs = 0.f;
#pragma unroll
            for (int j = 0; j < 4; j++) {
                p[j] = __expf(sacc[i][j] - mnew);
                rs += p[j];
            }
#pragma unroll
            for (int mm = 1; mm < 16; mm <<= 1)
                rs += __shfl_xor(rs, mm);
            l_run[i] = l_run[i] * sc + rs;
            m_run[i] = mnew;
#pragma unroll
            for (int j = 0; j < 4; j++) O[i][j] *= sc;
            float4 pv; pv.x = p[0]; pv.y = p[1]; pv.z = p[2]; pv.w = p[3];
            *(float4*)&Ps[ty * 4 + i][tx * 4] = pv;
        }
        __syncthreads();  // S-phase reads of KVs done; Ps complete

        // Load V tile transposed [t][d] into KVs
#pragma unroll
        for (int u = 0; u < 4; u++) {
            float4 vv = *(const float4*)(Vp + (size_t)ld_d * S_LEN + t0 + ld_q + u * 4);
            KVs[ld_q + u * 4 + 0][ld_d] = vv.x;
            KVs[ld_q + u * 4 + 1][ld_d] = vv.y;
            KVs[ld_q + u * 4 + 2][ld_d] = vv.z;
            KVs[ld_q + u * 4 + 3][ld_d] = vv.w;
        }
        __syncthreads();

        // O[s][d] += P[s][t] * V[d][t]   (KVs holds V^T: [t][d])
#pragma unroll 8
        for (int t = 0; t < 64; t++) {
            float4 vv = *(float4*)&KVs[t][tx * 4];
            float pa[4];
#pragma unroll
            for (int i = 0; i < 4; i++) pa[i] = Ps[ty * 4 + i][t];
#pragma unroll
            for (int i = 0; i < 4; i++) {
                O[i][0] = fmaf(pa[i], vv.x, O[i][0]);
                O[i][1] = fmaf(pa[i], vv.y, O[i][1]);
                O[i][2] = fmaf(pa[i], vv.z, O[i][2]);
                O[i][3] = fmaf(pa[i], vv.w, O[i][3]);
            }
        }
    }

    __syncthreads();
    // Normalize and transpose through LDS: Ps becomes [d][s]
#pragma unroll
    for (int i = 0; i < 4; i++) {
        float inv = 1.0f / l_run[i];
#pragma unroll
        for (int j = 0; j < 4; j++)
            Ps[tx * 4 + j][ty * 4 + i] = O[i][j] * inv;
    }
    __syncthreads();

    float* obase = out + ((size_t)b * 512 + (size_t)h * HDIM) * S_LEN;
#pragma unroll
    for (int u = 0; u < 4; u++) {
        *(float4*)(obase + (size_t)ld_d * S_LEN + s0 + ld_q + u * 4) =
            *(float4*)&Ps[ld_d][ld_q + u * 4];
    }
}

// ---------------------------------------------------------------------------
extern "C" void kernel_launch(void* const* d_in, const int* in_sizes, int n_in,
                              void* d_out, int out_size, void* d_ws, size_t ws_size,
                              hipStream_t stream)
{
    const float* x    = (const float*)d_in[0];
    const float* Wqkv = (const float*)d_in[1];
    const float* bqkv = (const float*)d_in[2];
    const float* Wout = (const float*)d_in[3];
    const float* bout = (const float*)d_in[4];
    float* out = (float*)d_out;

    float* qkv = (float*)d_ws;                          // [4][1536][2304]
    float* att = qkv + (size_t)4 * 1536 * S_LEN;        // [4][512][2304]

    dim3 blk(256);
    // QKV projection: M=1536
    gemm_proj<<<dim3(S_LEN / 128, 1536 / 128, 4), blk, 0, stream>>>(
        Wqkv, bqkv, x, qkv, 1536);
    // Attention
    attn_fwd<<<dim3(S_LEN / 64, NHEAD, 4), blk, 0, stream>>>(qkv, att);
    // Output projection: M=512
    gemm_proj<<<dim3(S_LEN / 128, 512 / 128, 4), blk, 0, stream>>>(
        Wout, bout, att, out, 512);
}

// Round 2
// 436.044 us; speedup vs baseline: 2.3414x; 2.3414x over previous
//
#include <hip/hip_runtime.h>

#define S_LEN 2304   // 48*48
#define K_DIM 512    // C
#define NHEAD 8

typedef __attribute__((ext_vector_type(4))) float f32x4;
typedef __attribute__((ext_vector_type(8))) short bf16x8;

// round-to-nearest-even f32 -> bf16 (inputs are finite)
__device__ __forceinline__ unsigned short f2bf(float f) {
    union { float f; unsigned u; } v; v.f = f;
    unsigned r = v.u + 0x7fffu + ((v.u >> 16) & 1u);
    return (unsigned short)(r >> 16);
}

// swizzled BYTE offset within a 64x64 bf16 tile (128B rows, 16B-block XOR)
__device__ __forceinline__ int swz(int row, int colbyte) {
    return row * 128 + (colbyte ^ ((row & 7) << 4));
}

// ---------------------------------------------------------------------------
// Generic projection GEMM (fp32, unchanged from R1): Y = W*X + bias
// ---------------------------------------------------------------------------
__global__ __launch_bounds__(256) void gemm_proj(
    const float* __restrict__ W, const float* __restrict__ bias,
    const float* __restrict__ X, float* __restrict__ Y, int M)
{
    const int N = S_LEN, K = K_DIM;
    const int n0 = blockIdx.x * 128;
    const int m0 = blockIdx.y * 128;
    const int b  = blockIdx.z;

    __shared__ float As[16][132];
    __shared__ float Bs[16][132];

    const float* Xb = X + (size_t)b * K * N;
    float*       Yb = Y + (size_t)b * M * N;

    const int tid = threadIdx.x;
    const int tx  = tid & 15;
    const int ty  = tid >> 4;

    float acc[8][8];
#pragma unroll
    for (int i = 0; i < 8; i++)
#pragma unroll
        for (int j = 0; j < 8; j++) acc[i][j] = 0.f;

    for (int k0 = 0; k0 < K; k0 += 16) {
#pragma unroll
        for (int p = 0; p < 2; p++) {
            int idx = tid + p * 256;
            int m   = idx >> 2;
            int kq  = (idx & 3) << 2;
            float4 a = *(const float4*)(W + (size_t)(m0 + m) * K + k0 + kq);
            As[kq + 0][m] = a.x;
            As[kq + 1][m] = a.y;
            As[kq + 2][m] = a.z;
            As[kq + 3][m] = a.w;
        }
#pragma unroll
        for (int p = 0; p < 2; p++) {
            int idx = tid + p * 256;
            int kk  = idx >> 5;
            int nq  = (idx & 31) << 2;
            *(float4*)&Bs[kk][nq] =
                *(const float4*)(Xb + (size_t)(k0 + kk) * N + n0 + nq);
        }
        __syncthreads();

#pragma unroll
        for (int k = 0; k < 16; k++) {
            float a[8], bb[8];
            *(float4*)&a[0]  = *(float4*)&As[k][ty * 8];
            *(float4*)&a[4]  = *(float4*)&As[k][ty * 8 + 4];
            *(float4*)&bb[0] = *(float4*)&Bs[k][tx * 8];
            *(float4*)&bb[4] = *(float4*)&Bs[k][tx * 8 + 4];
#pragma unroll
            for (int i = 0; i < 8; i++)
#pragma unroll
                for (int j = 0; j < 8; j++)
                    acc[i][j] = fmaf(a[i], bb[j], acc[i][j]);
        }
        __syncthreads();
    }

#pragma unroll
    for (int i = 0; i < 8; i++) {
        int m = m0 + ty * 8 + i;
        float bv = bias[m];
        float4 o0, o1;
        o0.x = acc[i][0] + bv; o0.y = acc[i][1] + bv;
        o0.z = acc[i][2] + bv; o0.w = acc[i][3] + bv;
        o1.x = acc[i][4] + bv; o1.y = acc[i][5] + bv;
        o1.z = acc[i][6] + bv; o1.w = acc[i][7] + bv;
        float* yrow = Yb + (size_t)m * N + n0 + tx * 8;
        *(float4*)yrow       = o0;
        *(float4*)(yrow + 4) = o1;
    }
}

// ---------------------------------------------------------------------------
// Flash attention, bf16 MFMA (swapped-QK). qkv: [B][3*512][S], out: [B][512][S].
// Block = (s-tile 64, h, b), 256 threads = 4 waves; wave w owns query cols
// s = 16w..16w+15. All LDS tiles 64x64 bf16, 128B rows, 16B XOR swizzle.
//   Qs[s][d], Ks[t][d]  (transposed at stage), Vs[d][t] (natural), Ps[s][t].
// S^T = mfma(Kfrag, Qfrag): lane holds S^T[t=16tb+4g+r][s=16w+ln].
// PV  = mfma(Vfrag, Pfrag): lane holds O[d=16db+4g+r][s=16w+ln].
// ---------------------------------------------------------------------------
__global__ __launch_bounds__(256) void attn_fwd_bf16(
    const float* __restrict__ qkv, float* __restrict__ out)
{
    const int s0 = blockIdx.x * 64;
    const int h  = blockIdx.y;
    const int b  = blockIdx.z;
    const size_t hb = ((size_t)b * 1536 + (size_t)h * 64) * S_LEN;
    const float* Qg = qkv + hb;
    const float* Kg = qkv + hb + (size_t)512  * S_LEN;
    const float* Vg = qkv + hb + (size_t)1024 * S_LEN;

    __shared__ unsigned short Qs[64 * 64];
    __shared__ unsigned short Ks[64 * 64];
    __shared__ unsigned short Vs[64 * 64];
    __shared__ unsigned short Ps[64 * 64];

    const int tid  = threadIdx.x;
    const int lane = tid & 63;
    const int w    = tid >> 6;
    const int g    = lane >> 4;
    const int ln   = lane & 15;

    // ---- stage Q transposed: Qs[s][d] <- Qg[d][s0+s]
    {
        const int d0 = (tid >> 5) * 8;   // d-oct
        const int t0 = (tid & 31) * 2;   // s-pair
        float2 r[8];
#pragma unroll
        for (int j = 0; j < 8; j++)
            r[j] = *(const float2*)(Qg + (size_t)(d0 + j) * S_LEN + s0 + t0);
        unsigned short w0[8], w1[8];
#pragma unroll
        for (int j = 0; j < 8; j++) { w0[j] = f2bf(r[j].x); w1[j] = f2bf(r[j].y); }
        *(bf16x8*)((char*)Qs + swz(t0,     d0 * 2)) = *(bf16x8*)w0;
        *(bf16x8*)((char*)Qs + swz(t0 + 1, d0 * 2)) = *(bf16x8*)w1;
    }

    float m_run = -1e30f, l_run = 0.f;
    f32x4 oacc[4];
#pragma unroll
    for (int i = 0; i < 4; i++) oacc[i] = (f32x4)0.f;

    for (int kt = 0; kt < S_LEN; kt += 64) {
        __syncthreads();   // prev tile compute done with Ks/Vs; Qs visible (iter 0)

        // ---- stage K transposed: Ks[t][d] <- Kg[d][kt+t]
        {
            const int d0 = (tid >> 5) * 8;
            const int t0 = (tid & 31) * 2;
            float2 r[8];
#pragma unroll
            for (int j = 0; j < 8; j++)
                r[j] = *(const float2*)(Kg + (size_t)(d0 + j) * S_LEN + kt + t0);
            unsigned short w0[8], w1[8];
#pragma unroll
            for (int j = 0; j < 8; j++) { w0[j] = f2bf(r[j].x); w1[j] = f2bf(r[j].y); }
            *(bf16x8*)((char*)Ks + swz(t0,     d0 * 2)) = *(bf16x8*)w0;
            *(bf16x8*)((char*)Ks + swz(t0 + 1, d0 * 2)) = *(bf16x8*)w1;
        }
        // ---- stage V natural: Vs[d][t] <- Vg[d][kt+t]
        {
            const int d = tid >> 2;
#pragma unroll
            for (int oo = 0; oo < 2; oo++) {
                const int oct = (tid & 3) + oo * 4;
                float4 a = *(const float4*)(Vg + (size_t)d * S_LEN + kt + oct * 8);
                float4 c = *(const float4*)(Vg + (size_t)d * S_LEN + kt + oct * 8 + 4);
                unsigned short ww[8] = { f2bf(a.x), f2bf(a.y), f2bf(a.z), f2bf(a.w),
                                         f2bf(c.x), f2bf(c.y), f2bf(c.z), f2bf(c.w) };
                *(bf16x8*)((char*)Vs + swz(d, oct * 16)) = *(bf16x8*)ww;
            }
        }
        __syncthreads();

        // ---- S^T tile: sacc[tb] holds S^T[16tb+4g+r][16w+ln]
        f32x4 sacc[4];
#pragma unroll
        for (int tb = 0; tb < 4; tb++) sacc[tb] = (f32x4)0.f;
#pragma unroll
        for (int c = 0; c < 2; c++) {
            bf16x8 qf = *(const bf16x8*)((char*)Qs + swz(16 * w + ln, c * 64 + g * 16));
#pragma unroll
            for (int tb = 0; tb < 4; tb++) {
                bf16x8 kf = *(const bf16x8*)((char*)Ks + swz(tb * 16 + ln, c * 64 + g * 16));
                sacc[tb] = __builtin_amdgcn_mfma_f32_16x16x32_bf16(kf, qf, sacc[tb], 0, 0, 0);
            }
        }

        // ---- online softmax; lane's query column is fixed (s = s0+16w+ln)
        float mloc = -1e30f;
#pragma unroll
        for (int tb = 0; tb < 4; tb++)
#pragma unroll
            for (int rr = 0; rr < 4; rr++) {
                float vsc = sacc[tb][rr] * 0.125f;   // 1/sqrt(64)
                sacc[tb][rr] = vsc;
                mloc = fmaxf(mloc, vsc);
            }
        mloc = fmaxf(mloc, __shfl_xor(mloc, 16));
        mloc = fmaxf(mloc, __shfl_xor(mloc, 32));
        const float mnew = fmaxf(m_run, mloc);
        const float resc = __expf(m_run - mnew);
        float rsum = 0.f;
        unsigned short pb[16];
#pragma unroll
        for (int tb = 0; tb < 4; tb++)
#pragma unroll
            for (int rr = 0; rr < 4; rr++) {
                float p = __expf(sacc[tb][rr] - mnew);
                rsum += p;
                pb[tb * 4 + rr] = f2bf(p);
            }
        rsum += __shfl_xor(rsum, 16);
        rsum += __shfl_xor(rsum, 32);
        l_run = l_run * resc + rsum;
        m_run = mnew;
#pragma unroll
        for (int db = 0; db < 4; db++)
#pragma unroll
            for (int rr = 0; rr < 4; rr++) oacc[db][rr] *= resc;

        // ---- write P rows (wave-private): Ps[16w+ln][16tb+4g .. +3]
#pragma unroll
        for (int tb = 0; tb < 4; tb++)
            *(unsigned long long*)((char*)Ps + swz(16 * w + ln, tb * 32 + g * 8)) =
                *(unsigned long long*)&pb[tb * 4];

        // ---- O += V * P  (same-wave LDS dep; compiler inserts lgkmcnt wait)
#pragma unroll
        for (int c = 0; c < 2; c++) {
            bf16x8 pf = *(const bf16x8*)((char*)Ps + swz(16 * w + ln, c * 64 + g * 16));
#pragma unroll
            for (int db = 0; db < 4; db++) {
                bf16x8 vf = *(const bf16x8*)((char*)Vs + swz(db * 16 + ln, c * 64 + g * 16));
                oacc[db] = __builtin_amdgcn_mfma_f32_16x16x32_bf16(vf, pf, oacc[db], 0, 0, 0);
            }
        }
    }

    // ---- epilogue: out[b][h*64+d][s0+16w+ln] = O[d]/l
    const float inv = 1.0f / l_run;
    float* ob = out + ((size_t)b * 512 + (size_t)h * 64) * S_LEN + s0 + 16 * w + ln;
#pragma unroll
    for (int db = 0; db < 4; db++)
#pragma unroll
        for (int rr = 0; rr < 4; rr++)
            ob[(size_t)(db * 16 + 4 * g + rr) * S_LEN] = oacc[db][rr] * inv;
}

// ---------------------------------------------------------------------------
extern "C" void kernel_launch(void* const* d_in, const int* in_sizes, int n_in,
                              void* d_out, int out_size, void* d_ws, size_t ws_size,
                              hipStream_t stream)
{
    const float* x    = (const float*)d_in[0];
    const float* Wqkv = (const float*)d_in[1];
    const float* bqkv = (const float*)d_in[2];
    const float* Wout = (const float*)d_in[3];
    const float* bout = (const float*)d_in[4];
    float* out = (float*)d_out;

    float* qkv = (float*)d_ws;                          // [4][1536][2304]
    float* att = qkv + (size_t)4 * 1536 * S_LEN;        // [4][512][2304]

    dim3 blk(256);
    gemm_proj<<<dim3(S_LEN / 128, 1536 / 128, 4), blk, 0, stream>>>(
        Wqkv, bqkv, x, qkv, 1536);
    attn_fwd_bf16<<<dim3(S_LEN / 64, NHEAD, 4), blk, 0, stream>>>(qkv, att);
    gemm_proj<<<dim3(S_LEN / 128, 512 / 128, 4), blk, 0, stream>>>(
        Wout, bout, att, out, 512);
}

// Round 4
// 168.031 us; speedup vs baseline: 6.0760x; 2.5950x over previous
//
#include <hip/hip_runtime.h>

#define S_LEN 2304   // 48*48
#define CDIM  512
#define NHEAD 8

typedef __attribute__((ext_vector_type(4))) float f32x4;
typedef __attribute__((ext_vector_type(8))) _Float16 f16x8;
typedef _Float16 h16;

// async global->LDS, 16B per lane; LDS dest = wave-uniform base + lane*16
__device__ __forceinline__ void gll16(const h16* g, h16* l) {
    __builtin_amdgcn_global_load_lds(
        (const __attribute__((address_space(1))) unsigned int*)g,
        (__attribute__((address_space(3))) unsigned int*)l, 16, 0, 0);
}

// ---------------------------------------------------------------------------
// Kernel 0a: transpose+convert x[b][c][s] fp32 -> xT[b][s][c] fp16
// ---------------------------------------------------------------------------
__global__ __launch_bounds__(256) void xpose_x(
    const float* __restrict__ x, h16* __restrict__ xT)
{
    const int s0 = blockIdx.x * 64;
    const int c0 = blockIdx.y * 64;
    const int b  = blockIdx.z;
    __shared__ h16 Ts[64][76];

    const int t  = threadIdx.x;
    const int cq = t >> 4;    // 0..15
    const int sq = t & 15;    // 0..15

    const float* xb = x + ((size_t)b * CDIM + c0 + cq * 4) * S_LEN + s0 + sq * 4;
    float4 r0 = *(const float4*)(xb);
    float4 r1 = *(const float4*)(xb + S_LEN);
    float4 r2 = *(const float4*)(xb + 2 * S_LEN);
    float4 r3 = *(const float4*)(xb + 3 * S_LEN);

    union { h16 h[4]; uint2 u; } pk;
    pk.h[0]=(h16)r0.x; pk.h[1]=(h16)r1.x; pk.h[2]=(h16)r2.x; pk.h[3]=(h16)r3.x;
    *(uint2*)&Ts[sq*4+0][cq*4] = pk.u;
    pk.h[0]=(h16)r0.y; pk.h[1]=(h16)r1.y; pk.h[2]=(h16)r2.y; pk.h[3]=(h16)r3.y;
    *(uint2*)&Ts[sq*4+1][cq*4] = pk.u;
    pk.h[0]=(h16)r0.z; pk.h[1]=(h16)r1.z; pk.h[2]=(h16)r2.z; pk.h[3]=(h16)r3.z;
    *(uint2*)&Ts[sq*4+2][cq*4] = pk.u;
    pk.h[0]=(h16)r0.w; pk.h[1]=(h16)r1.w; pk.h[2]=(h16)r2.w; pk.h[3]=(h16)r3.w;
    *(uint2*)&Ts[sq*4+3][cq*4] = pk.u;

    __syncthreads();
    const int s  = t >> 2;
    const int cc = (t & 3) * 16;
    uint2 a0 = *(uint2*)&Ts[s][cc + 0];
    uint2 a1 = *(uint2*)&Ts[s][cc + 4];
    uint2 a2 = *(uint2*)&Ts[s][cc + 8];
    uint2 a3 = *(uint2*)&Ts[s][cc + 12];
    h16* dst = xT + ((size_t)b * S_LEN + s0 + s) * CDIM + c0 + cc;
    uint4 w0 = make_uint4(a0.x, a0.y, a1.x, a1.y);
    uint4 w1 = make_uint4(a2.x, a2.y, a3.x, a3.y);
    *(uint4*)dst       = w0;
    *(uint4*)(dst + 8) = w1;
}

// ---------------------------------------------------------------------------
// Kernel 0b: convert Wqkv (1536x512) and Wout (512x512) fp32 -> fp16
// total = (1536*512 + 512*512) / 4 per-thread = 262144 threads = 1024 blocks
// ---------------------------------------------------------------------------
__global__ __launch_bounds__(256) void wconv(
    const float* __restrict__ Wq, const float* __restrict__ Wo,
    h16* __restrict__ Wq_h, h16* __restrict__ Wo_h)
{
    const int NQ = 1536 * 512;
    const int NO = 512 * 512;
    int i = (blockIdx.x * 256 + threadIdx.x) * 4;
    if (i >= NQ + NO) return;
    float4 v;
    h16* dst;
    if (i < NQ) { v = *(const float4*)(Wq + i);        dst = Wq_h + i; }
    else        { v = *(const float4*)(Wo + (i - NQ)); dst = Wo_h + (i - NQ); }
    union { h16 h[4]; uint2 u; } pk;
    pk.h[0]=(h16)v.x; pk.h[1]=(h16)v.y; pk.h[2]=(h16)v.z; pk.h[3]=(h16)v.w;
    *(uint2*)dst = pk.u;
}

// ---------------------------------------------------------------------------
// Kernel 1: QKV projection, fp16 MFMA. Wh[m][k] fp16, xT[b][n][k] fp16.
// q/k blocks (m0<1024): D[m][n] = mfma(Wf, Xf) -> write qT/kT[b][h][s][d].
// v  blocks (m0>=1024): D[n][m] = mfma(Xf, Wf) -> write v[b][h][d][s].
// 128x128 tile, BK=64, 4 waves (2x2), global_load_lds staging w/ XOR swizzle.
// ---------------------------------------------------------------------------
__global__ __launch_bounds__(256) void gemm_qkv(
    const h16* __restrict__ Wh, const float* __restrict__ bqkv,
    const h16* __restrict__ xT, h16* __restrict__ qT, h16* __restrict__ kT,
    h16* __restrict__ vN)
{
    const int n0 = blockIdx.x * 128;
    const int m0 = blockIdx.y * 128;
    const int b  = blockIdx.z;
    __shared__ h16 Ws[128 * 64];
    __shared__ h16 Xs[128 * 64];

    const int tid = threadIdx.x;
    const int lid = tid & 63, w = tid >> 6;
    const int g = lid >> 4, ln = lid & 15;
    const int wm = w & 1, wn = w >> 1;
    const int srow = lid >> 3;                    // 0..7 within 8-row chunk
    const int sblk = (lid & 7) ^ (srow & 7);      // pre-swizzled source col blk

    f32x4 acc[4][4];
#pragma unroll
    for (int i = 0; i < 4; i++)
#pragma unroll
        for (int j = 0; j < 4; j++) acc[i][j] = (f32x4)0.f;

    const h16* Wbase = Wh + (size_t)m0 * CDIM;
    const h16* Xbase = xT + ((size_t)b * S_LEN + n0) * CDIM;
    const bool vblk = (m0 >= 1024);

    for (int kt = 0; kt < CDIM; kt += 64) {
        __syncthreads();
#pragma unroll
        for (int i = 0; i < 4; i++) {
            const int row0 = w * 32 + i * 8;
            gll16(Wbase + (size_t)(row0 + srow) * CDIM + kt + sblk * 8, &Ws[row0 * 64]);
            gll16(Xbase + (size_t)(row0 + srow) * CDIM + kt + sblk * 8, &Xs[row0 * 64]);
        }
        __syncthreads();

#pragma unroll
        for (int kc = 0; kc < 2; kc++) {
            f16x8 af[4], bf[4];
#pragma unroll
            for (int i = 0; i < 4; i++) {
                const int ra = wm * 64 + i * 16 + ln;
                const int ca = (kc * 64 + g * 16) ^ ((ra & 7) << 4);
                af[i] = *(const f16x8*)&Ws[ra * 64 + ca / 2];
                const int rb = wn * 64 + i * 16 + ln;
                const int cb = (kc * 64 + g * 16) ^ ((rb & 7) << 4);
                bf[i] = *(const f16x8*)&Xs[rb * 64 + cb / 2];
            }
            if (!vblk) {
#pragma unroll
                for (int i = 0; i < 4; i++)
#pragma unroll
                    for (int j = 0; j < 4; j++)
                        acc[i][j] = __builtin_amdgcn_mfma_f32_16x16x32_f16(
                            af[i], bf[j], acc[i][j], 0, 0, 0);
            } else {
#pragma unroll
                for (int i = 0; i < 4; i++)
#pragma unroll
                    for (int j = 0; j < 4; j++)
                        acc[i][j] = __builtin_amdgcn_mfma_f32_16x16x32_f16(
                            bf[i], af[j], acc[i][j], 0, 0, 0);
            }
        }
    }

    if (!vblk) {
        // D[m][n]: lane n=ln fixed, m=4g+r contiguous -> qT/kT[b][h][s][d] 8B
#pragma unroll
        for (int i = 0; i < 4; i++) {
            const int mb = m0 + wm * 64 + i * 16 + 4 * g;
            const float4 bv = *(const float4*)&bqkv[mb];
            const int mloc = mb & 511;
            const int hh = mloc >> 6, d0 = mloc & 63;
            h16* base = (mb < 512 ? qT : kT);
#pragma unroll
            for (int j = 0; j < 4; j++) {
                const int n = n0 + wn * 64 + j * 16 + ln;
                union { h16 h[4]; uint2 u; } pk;
                pk.h[0] = (h16)(acc[i][j][0] + bv.x);
                pk.h[1] = (h16)(acc[i][j][1] + bv.y);
                pk.h[2] = (h16)(acc[i][j][2] + bv.z);
                pk.h[3] = (h16)(acc[i][j][3] + bv.w);
                *(uint2*)(base + (((size_t)b * 8 + hh) * S_LEN + n) * 64 + d0) = pk.u;
            }
        }
    } else {
        // D[n][m]: lane m=ln fixed, n=4g+r contiguous -> v[b][h][d][s] 8B
#pragma unroll
        for (int j = 0; j < 4; j++) {
            const int m = m0 + wm * 64 + j * 16 + ln;
            const float bias = bqkv[m];
            const int mloc = m - 1024;
            const int hh = mloc >> 6, d = mloc & 63;
            h16* base = vN + (((size_t)b * 8 + hh) * 64 + d) * S_LEN;
#pragma unroll
            for (int i = 0; i < 4; i++) {
                const int nb = n0 + wn * 64 + i * 16 + 4 * g;
                union { h16 h[4]; uint2 u; } pk;
                pk.h[0] = (h16)(acc[i][j][0] + bias);
                pk.h[1] = (h16)(acc[i][j][1] + bias);
                pk.h[2] = (h16)(acc[i][j][2] + bias);
                pk.h[3] = (h16)(acc[i][j][3] + bias);
                *(uint2*)(base + nb) = pk.u;
            }
        }
    }
}

// ---------------------------------------------------------------------------
// Kernel 2: flash attention fp16. qT/kT[b][h][s|t][d], v[b][h][d][s] fp16.
// Out: attT[b][s][c] fp16 (transposed for the out-proj GEMM).
// Block = (64-s tile, h, b), 4 waves; wave w owns query cols s=16w..16w+15.
// ---------------------------------------------------------------------------
__global__ __launch_bounds__(256) void attn_f16(
    const h16* __restrict__ qT, const h16* __restrict__ kT,
    const h16* __restrict__ vN, h16* __restrict__ attT)
{
    const int s0 = blockIdx.x * 64;
    const int h  = blockIdx.y;
    const int b  = blockIdx.z;
    __shared__ h16 Qs[64 * 64];
    __shared__ h16 Ks[64 * 64];
    __shared__ h16 Vs[64 * 64];
    __shared__ h16 Ps[64 * 64];

    const int tid = threadIdx.x;
    const int lid = tid & 63, w = tid >> 6;
    const int g = lid >> 4, ln = lid & 15;
    const int srow = lid >> 3;
    const int sblk = (lid & 7) ^ (srow & 7);

    const h16* qb = qT + ((size_t)b * 8 + h) * S_LEN * 64;
    const h16* kb = kT + ((size_t)b * 8 + h) * S_LEN * 64;
    const h16* vb = vN + ((size_t)b * 8 + h) * 64 * S_LEN;

    // stage Q once: Qs[s][d]
#pragma unroll
    for (int i = 0; i < 2; i++) {
        const int row0 = w * 16 + i * 8;
        gll16(qb + (size_t)(s0 + row0 + srow) * 64 + sblk * 8, &Qs[row0 * 64]);
    }

    float m_run = -1e30f, l_run = 0.f;
    f32x4 oacc[4];
#pragma unroll
    for (int i = 0; i < 4; i++) oacc[i] = (f32x4)0.f;

    for (int kt = 0; kt < S_LEN; kt += 64) {
        __syncthreads();   // prev compute done with Ks/Vs (drains Q gll, iter 0)
#pragma unroll
        for (int i = 0; i < 2; i++) {
            const int row0 = w * 16 + i * 8;
            gll16(kb + (size_t)(kt + row0 + srow) * 64 + sblk * 8, &Ks[row0 * 64]);
            gll16(vb + (size_t)(row0 + srow) * S_LEN + kt + sblk * 8, &Vs[row0 * 64]);
        }
        __syncthreads();

        // S^T = mfma(Kf, Qf): lane holds S^T[t=16tb+4g+r][s=16w+ln]
        f32x4 sacc[4];
#pragma unroll
        for (int tb = 0; tb < 4; tb++) sacc[tb] = (f32x4)0.f;
#pragma unroll
        for (int c = 0; c < 2; c++) {
            const int cq = (c * 64 + g * 16) ^ ((ln & 7) << 4);
            f16x8 qf = *(const f16x8*)&Qs[(16 * w + ln) * 64 + cq / 2];
#pragma unroll
            for (int tb = 0; tb < 4; tb++) {
                const int row = tb * 16 + ln;
                const int cb = (c * 64 + g * 16) ^ ((row & 7) << 4);
                f16x8 kf = *(const f16x8*)&Ks[row * 64 + cb / 2];
                sacc[tb] = __builtin_amdgcn_mfma_f32_16x16x32_f16(kf, qf, sacc[tb], 0, 0, 0);
            }
        }

        // online softmax over the lane's query column
        float mloc = -1e30f;
#pragma unroll
        for (int tb = 0; tb < 4; tb++)
#pragma unroll
            for (int r = 0; r < 4; r++) {
                const float vsc = sacc[tb][r] * 0.125f;   // 1/sqrt(64)
                sacc[tb][r] = vsc;
                mloc = fmaxf(mloc, vsc);
            }
        mloc = fmaxf(mloc, __shfl_xor(mloc, 16));
        mloc = fmaxf(mloc, __shfl_xor(mloc, 32));
        const float mnew = fmaxf(m_run, mloc);
        const float resc = __expf(m_run - mnew);
        float rsum = 0.f;
        union { h16 h[4]; uint2 u; } pk[4];
#pragma unroll
        for (int tb = 0; tb < 4; tb++)
#pragma unroll
            for (int r = 0; r < 4; r++) {
                const float p = __expf(sacc[tb][r] - mnew);
                rsum += p;
                pk[tb].h[r] = (h16)p;
            }
        rsum += __shfl_xor(rsum, 16);
        rsum += __shfl_xor(rsum, 32);
        l_run = l_run * resc + rsum;
        m_run = mnew;
#pragma unroll
        for (int db = 0; db < 4; db++)
#pragma unroll
            for (int r = 0; r < 4; r++) oacc[db][r] *= resc;

        // P rows (wave-private): Ps[16w+ln][t]
#pragma unroll
        for (int tb = 0; tb < 4; tb++) {
            const int cb = (tb * 32 + g * 8) ^ ((ln & 7) << 4);
            *(uint2*)&Ps[(16 * w + ln) * 64 + cb / 2] = pk[tb].u;
        }

        // O += mfma(Vf, Pf): lane holds O[d=16db+4g+r][s=16w+ln]
#pragma unroll
        for (int c = 0; c < 2; c++) {
            const int cp = (c * 64 + g * 16) ^ ((ln & 7) << 4);
            f16x8 pf = *(const f16x8*)&Ps[(16 * w + ln) * 64 + cp / 2];
#pragma unroll
            for (int db = 0; db < 4; db++) {
                const int row = db * 16 + ln;
                const int cb = (c * 64 + g * 16) ^ ((row & 7) << 4);
                f16x8 vf = *(const f16x8*)&Vs[row * 64 + cb / 2];
                oacc[db] = __builtin_amdgcn_mfma_f32_16x16x32_f16(vf, pf, oacc[db], 0, 0, 0);
            }
        }
    }

    // epilogue: attT[b][s0+16w+ln][h*64 + d], 8B chunks
    const float inv = 1.0f / l_run;
    h16* ob = attT + ((size_t)b * S_LEN + s0 + 16 * w + ln) * CDIM + h * 64;
#pragma unroll
    for (int db = 0; db < 4; db++) {
        union { h16 h[4]; uint2 u; } pk;
#pragma unroll
        for (int r = 0; r < 4; r++) pk.h[r] = (h16)(oacc[db][r] * inv);
        *(uint2*)(ob + db * 16 + 4 * g) = pk.u;
    }
}

// ---------------------------------------------------------------------------
// Kernel 3: output projection. A=attT[b][n][k], B=Wout_h[m][k].
// D[n][m] = mfma(Xf, Wf): lane m=ln fixed, n=4g+r contiguous -> 16B f32 stores.
// ---------------------------------------------------------------------------
__global__ __launch_bounds__(256) void gemm_out(
    const h16* __restrict__ attT, const h16* __restrict__ Wh,
    const float* __restrict__ bout, float* __restrict__ out)
{
    const int n0 = blockIdx.x * 128;
    const int m0 = blockIdx.y * 128;
    const int b  = blockIdx.z;
    __shared__ h16 Ws[128 * 64];
    __shared__ h16 Xs[128 * 64];

    const int tid = threadIdx.x;
    const int lid = tid & 63, w = tid >> 6;
    const int g = lid >> 4, ln = lid & 15;
    const int wm = w & 1, wn = w >> 1;
    const int srow = lid >> 3;
    const int sblk = (lid & 7) ^ (srow & 7);

    f32x4 acc[4][4];
#pragma unroll
    for (int i = 0; i < 4; i++)
#pragma unroll
        for (int j = 0; j < 4; j++) acc[i][j] = (f32x4)0.f;

    const h16* Wbase = Wh + (size_t)m0 * CDIM;
    const h16* Xbase = attT + ((size_t)b * S_LEN + n0) * CDIM;

    for (int kt = 0; kt < CDIM; kt += 64) {
        __syncthreads();
#pragma unroll
        for (int i = 0; i < 4; i++) {
            const int row0 = w * 32 + i * 8;
            gll16(Wbase + (size_t)(row0 + srow) * CDIM + kt + sblk * 8, &Ws[row0 * 64]);
            gll16(Xbase + (size_t)(row0 + srow) * CDIM + kt + sblk * 8, &Xs[row0 * 64]);
        }
        __syncthreads();

#pragma unroll
        for (int kc = 0; kc < 2; kc++) {
            f16x8 af[4], bf[4];
#pragma unroll
            for (int i = 0; i < 4; i++) {
                const int ra = wm * 64 + i * 16 + ln;
                const int ca = (kc * 64 + g * 16) ^ ((ra & 7) << 4);
                af[i] = *(const f16x8*)&Ws[ra * 64 + ca / 2];
                const int rb = wn * 64 + i * 16 + ln;
                const int cb = (kc * 64 + g * 16) ^ ((rb & 7) << 4);
                bf[i] = *(const f16x8*)&Xs[rb * 64 + cb / 2];
            }
#pragma unroll
            for (int i = 0; i < 4; i++)
#pragma unroll
                for (int j = 0; j < 4; j++)
                    acc[i][j] = __builtin_amdgcn_mfma_f32_16x16x32_f16(
                        bf[i], af[j], acc[i][j], 0, 0, 0);
        }
    }

#pragma unroll
    for (int j = 0; j < 4; j++) {
        const int m = m0 + wm * 64 + j * 16 + ln;
        const float bias = bout[m];
        float* base = out + ((size_t)b * CDIM + m) * S_LEN;
#pragma unroll
        for (int i = 0; i < 4; i++) {
            const int nb = n0 + wn * 64 + i * 16 + 4 * g;
            float4 o;
            o.x = acc[i][j][0] + bias;
            o.y = acc[i][j][1] + bias;
            o.z = acc[i][j][2] + bias;
            o.w = acc[i][j][3] + bias;
            *(float4*)(base + nb) = o;
        }
    }
}

// ---------------------------------------------------------------------------
extern "C" void kernel_launch(void* const* d_in, const int* in_sizes, int n_in,
                              void* d_out, int out_size, void* d_ws, size_t ws_size,
                              hipStream_t stream)
{
    const float* x    = (const float*)d_in[0];
    const float* Wqkv = (const float*)d_in[1];
    const float* bqkv = (const float*)d_in[2];
    const float* Wout = (const float*)d_in[3];
    const float* bout = (const float*)d_in[4];
    float* out = (float*)d_out;

    h16* xT   = (h16*)d_ws;                          // [4][2304][512]
    h16* Wq_h = xT   + (size_t)4 * S_LEN * CDIM;     // [1536][512]
    h16* Wo_h = Wq_h + (size_t)1536 * 512;           // [512][512]
    h16* qT   = Wo_h + (size_t)512 * 512;            // [4][8][2304][64]
    h16* kT   = qT   + (size_t)4 * 8 * S_LEN * 64;
    h16* vN   = kT   + (size_t)4 * 8 * S_LEN * 64;   // [4][8][64][2304]
    h16* attT = vN   + (size_t)4 * 8 * S_LEN * 64;   // [4][2304][512]

    xpose_x <<<dim3(36, 8, 4),  256, 0, stream>>>(x, xT);
    wconv   <<<1024,            256, 0, stream>>>(Wqkv, Wout, Wq_h, Wo_h);
    gemm_qkv<<<dim3(18, 12, 4), 256, 0, stream>>>(Wq_h, bqkv, xT, qT, kT, vN);
    attn_f16<<<dim3(36, 8, 4),  256, 0, stream>>>(qT, kT, vN, attT);
    gemm_out<<<dim3(18, 4, 4),  256, 0, stream>>>(attT, Wo_h, bout, out);
}

// Round 6
// 156.446 us; speedup vs baseline: 6.5259x; 1.0741x over previous
//
#include <hip/hip_runtime.h>

#define S_LEN 2304   // 48*48
#define CDIM  512
#define NHEAD 8

typedef __attribute__((ext_vector_type(4))) float f32x4;
typedef __attribute__((ext_vector_type(8))) _Float16 f16x8;
typedef __attribute__((ext_vector_type(2))) __fp16 fp16x2r;  // cvt_pkrtz native type
typedef _Float16 h16;

// softmax runs in exp2 domain: q pre-scaled by 1/sqrt(64) * log2(e)
#define QSCALE 0.18033688011112042f

__device__ __forceinline__ float fexp2(float x) {
#if __has_builtin(__builtin_amdgcn_exp2f)
    return __builtin_amdgcn_exp2f(x);
#else
    return exp2f(x);
#endif
}

// async global->LDS, 16B per lane; LDS dest = wave-uniform base + lane*16
__device__ __forceinline__ void gll16(const h16* g, h16* l) {
    __builtin_amdgcn_global_load_lds(
        (const __attribute__((address_space(1))) unsigned int*)g,
        (__attribute__((address_space(3))) unsigned int*)l, 16, 0, 0);
}

// ---------------------------------------------------------------------------
// Kernel 0a: transpose+convert x[b][c][s] fp32 -> xT[b][s][c] fp16
// ---------------------------------------------------------------------------
__global__ __launch_bounds__(256) void xpose_x(
    const float* __restrict__ x, h16* __restrict__ xT)
{
    const int s0 = blockIdx.x * 64;
    const int c0 = blockIdx.y * 64;
    const int b  = blockIdx.z;
    __shared__ h16 Ts[64][76];

    const int t  = threadIdx.x;
    const int cq = t >> 4;
    const int sq = t & 15;

    const float* xb = x + ((size_t)b * CDIM + c0 + cq * 4) * S_LEN + s0 + sq * 4;
    float4 r0 = *(const float4*)(xb);
    float4 r1 = *(const float4*)(xb + S_LEN);
    float4 r2 = *(const float4*)(xb + 2 * S_LEN);
    float4 r3 = *(const float4*)(xb + 3 * S_LEN);

    union { h16 h[4]; uint2 u; } pk;
    pk.h[0]=(h16)r0.x; pk.h[1]=(h16)r1.x; pk.h[2]=(h16)r2.x; pk.h[3]=(h16)r3.x;
    *(uint2*)&Ts[sq*4+0][cq*4] = pk.u;
    pk.h[0]=(h16)r0.y; pk.h[1]=(h16)r1.y; pk.h[2]=(h16)r2.y; pk.h[3]=(h16)r3.y;
    *(uint2*)&Ts[sq*4+1][cq*4] = pk.u;
    pk.h[0]=(h16)r0.z; pk.h[1]=(h16)r1.z; pk.h[2]=(h16)r2.z; pk.h[3]=(h16)r3.z;
    *(uint2*)&Ts[sq*4+2][cq*4] = pk.u;
    pk.h[0]=(h16)r0.w; pk.h[1]=(h16)r1.w; pk.h[2]=(h16)r2.w; pk.h[3]=(h16)r3.w;
    *(uint2*)&Ts[sq*4+3][cq*4] = pk.u;

    __syncthreads();
    const int s  = t >> 2;
    const int cc = (t & 3) * 16;
    uint2 a0 = *(uint2*)&Ts[s][cc + 0];
    uint2 a1 = *(uint2*)&Ts[s][cc + 4];
    uint2 a2 = *(uint2*)&Ts[s][cc + 8];
    uint2 a3 = *(uint2*)&Ts[s][cc + 12];
    h16* dst = xT + ((size_t)b * S_LEN + s0 + s) * CDIM + c0 + cc;
    uint4 w0 = make_uint4(a0.x, a0.y, a1.x, a1.y);
    uint4 w1 = make_uint4(a2.x, a2.y, a3.x, a3.y);
    *(uint4*)dst       = w0;
    *(uint4*)(dst + 8) = w1;
}

// ---------------------------------------------------------------------------
// Kernel 0b: convert Wqkv (1536x512) and Wout (512x512) fp32 -> fp16
// ---------------------------------------------------------------------------
__global__ __launch_bounds__(256) void wconv(
    const float* __restrict__ Wq, const float* __restrict__ Wo,
    h16* __restrict__ Wq_h, h16* __restrict__ Wo_h)
{
    const int NQ = 1536 * 512;
    const int NO = 512 * 512;
    int i = (blockIdx.x * 256 + threadIdx.x) * 4;
    if (i >= NQ + NO) return;
    float4 v;
    h16* dst;
    if (i < NQ) { v = *(const float4*)(Wq + i);        dst = Wq_h + i; }
    else        { v = *(const float4*)(Wo + (i - NQ)); dst = Wo_h + (i - NQ); }
    union { h16 h[4]; uint2 u; } pk;
    pk.h[0]=(h16)v.x; pk.h[1]=(h16)v.y; pk.h[2]=(h16)v.z; pk.h[3]=(h16)v.w;
    *(uint2*)dst = pk.u;
}

// ---------------------------------------------------------------------------
// Kernel 1: QKV projection, fp16 MFMA. q rows get *QSCALE (softmax exp2 domain).
// ---------------------------------------------------------------------------
__global__ __launch_bounds__(256) void gemm_qkv(
    const h16* __restrict__ Wh, const float* __restrict__ bqkv,
    const h16* __restrict__ xT, h16* __restrict__ qT, h16* __restrict__ kT,
    h16* __restrict__ vN)
{
    const int n0 = blockIdx.x * 128;
    const int m0 = blockIdx.y * 128;
    const int b  = blockIdx.z;
    __shared__ h16 Ws[128 * 64];
    __shared__ h16 Xs[128 * 64];

    const int tid = threadIdx.x;
    const int lid = tid & 63, w = tid >> 6;
    const int g = lid >> 4, ln = lid & 15;
    const int wm = w & 1, wn = w >> 1;
    const int srow = lid >> 3;
    const int sblk = (lid & 7) ^ (srow & 7);

    f32x4 acc[4][4];
#pragma unroll
    for (int i = 0; i < 4; i++)
#pragma unroll
        for (int j = 0; j < 4; j++) acc[i][j] = (f32x4)0.f;

    const h16* Wbase = Wh + (size_t)m0 * CDIM;
    const h16* Xbase = xT + ((size_t)b * S_LEN + n0) * CDIM;
    const bool vblk = (m0 >= 1024);

    for (int kt = 0; kt < CDIM; kt += 64) {
        __syncthreads();
#pragma unroll
        for (int i = 0; i < 4; i++) {
            const int row0 = w * 32 + i * 8;
            gll16(Wbase + (size_t)(row0 + srow) * CDIM + kt + sblk * 8, &Ws[row0 * 64]);
            gll16(Xbase + (size_t)(row0 + srow) * CDIM + kt + sblk * 8, &Xs[row0 * 64]);
        }
        __syncthreads();

#pragma unroll
        for (int kc = 0; kc < 2; kc++) {
            f16x8 af[4], bf[4];
#pragma unroll
            for (int i = 0; i < 4; i++) {
                const int ra = wm * 64 + i * 16 + ln;
                const int ca = (kc * 64 + g * 16) ^ ((ra & 7) << 4);
                af[i] = *(const f16x8*)&Ws[ra * 64 + ca / 2];
                const int rb = wn * 64 + i * 16 + ln;
                const int cb = (kc * 64 + g * 16) ^ ((rb & 7) << 4);
                bf[i] = *(const f16x8*)&Xs[rb * 64 + cb / 2];
            }
            if (!vblk) {
#pragma unroll
                for (int i = 0; i < 4; i++)
#pragma unroll
                    for (int j = 0; j < 4; j++)
                        acc[i][j] = __builtin_amdgcn_mfma_f32_16x16x32_f16(
                            af[i], bf[j], acc[i][j], 0, 0, 0);
            } else {
#pragma unroll
                for (int i = 0; i < 4; i++)
#pragma unroll
                    for (int j = 0; j < 4; j++)
                        acc[i][j] = __builtin_amdgcn_mfma_f32_16x16x32_f16(
                            bf[i], af[j], acc[i][j], 0, 0, 0);
            }
        }
    }

    if (!vblk) {
#pragma unroll
        for (int i = 0; i < 4; i++) {
            const int mb = m0 + wm * 64 + i * 16 + 4 * g;
            const float4 bv = *(const float4*)&bqkv[mb];
            const int mloc = mb & 511;
            const int hh = mloc >> 6, d0 = mloc & 63;
            const bool isq = (mb < 512);
            const float scl = isq ? QSCALE : 1.0f;
            h16* base = (isq ? qT : kT);
#pragma unroll
            for (int j = 0; j < 4; j++) {
                const int n = n0 + wn * 64 + j * 16 + ln;
                union { h16 h[4]; uint2 u; } pk;
                pk.h[0] = (h16)((acc[i][j][0] + bv.x) * scl);
                pk.h[1] = (h16)((acc[i][j][1] + bv.y) * scl);
                pk.h[2] = (h16)((acc[i][j][2] + bv.z) * scl);
                pk.h[3] = (h16)((acc[i][j][3] + bv.w) * scl);
                *(uint2*)(base + (((size_t)b * 8 + hh) * S_LEN + n) * 64 + d0) = pk.u;
            }
        }
    } else {
#pragma unroll
        for (int j = 0; j < 4; j++) {
            const int m = m0 + wm * 64 + j * 16 + ln;
            const float bias = bqkv[m];
            const int mloc = m - 1024;
            const int hh = mloc >> 6, d = mloc & 63;
            h16* base = vN + (((size_t)b * 8 + hh) * 64 + d) * S_LEN;
#pragma unroll
            for (int i = 0; i < 4; i++) {
                const int nb = n0 + wn * 64 + i * 16 + 4 * g;
                union { h16 h[4]; uint2 u; } pk;
                pk.h[0] = (h16)(acc[i][j][0] + bias);
                pk.h[1] = (h16)(acc[i][j][1] + bias);
                pk.h[2] = (h16)(acc[i][j][2] + bias);
                pk.h[3] = (h16)(acc[i][j][3] + bias);
                *(uint2*)(base + nb) = pk.u;
            }
        }
    }
}

// ---------------------------------------------------------------------------
// Kernel 2: flash attention fp16, exp2-domain softmax.
//  - double-buffered K/V staging (one barrier per tile, latency hidden)
//  - defer-max: skip O/l rescale while tile max <= m_run + 8 (P <= 2^8, fp16-safe)
//  - l via ones-MFMA folded into PV (no per-lane rsum / shfl)
// ---------------------------------------------------------------------------
__global__ __launch_bounds__(256) void attn_f16(
    const h16* __restrict__ qT, const h16* __restrict__ kT,
    const h16* __restrict__ vN, h16* __restrict__ attT)
{
    const int s0 = blockIdx.x * 64;
    const int h  = blockIdx.y;
    const int b  = blockIdx.z;
    __shared__ h16 Qs[64 * 64];
    __shared__ h16 Ks[2][64 * 64];
    __shared__ h16 Vs[2][64 * 64];
    __shared__ h16 Ps[64 * 64];

    const int tid = threadIdx.x;
    const int lid = tid & 63, w = tid >> 6;
    const int g = lid >> 4, ln = lid & 15;
    const int srow = lid >> 3;
    const int sblk = (lid & 7) ^ (srow & 7);

    const h16* qb = qT + ((size_t)b * 8 + h) * S_LEN * 64;
    const h16* kb = kT + ((size_t)b * 8 + h) * S_LEN * 64;
    const h16* vb = vN + ((size_t)b * 8 + h) * 64 * S_LEN;

    // prologue: stage Q + tile 0 of K/V
#pragma unroll
    for (int i = 0; i < 2; i++) {
        const int row0 = w * 16 + i * 8;
        gll16(qb + (size_t)(s0 + row0 + srow) * 64 + sblk * 8, &Qs[row0 * 64]);
        gll16(kb + (size_t)(row0 + srow) * 64 + sblk * 8, &Ks[0][row0 * 64]);
        gll16(vb + (size_t)(row0 + srow) * S_LEN + sblk * 8, &Vs[0][row0 * 64]);
    }
    __syncthreads();

    f16x8 ones;
#pragma unroll
    for (int i = 0; i < 8; i++) ones[i] = (h16)1.0f;

    float m_run = -1e30f;
    f32x4 oacc[4], lacc;
#pragma unroll
    for (int i = 0; i < 4; i++) oacc[i] = (f32x4)0.f;
    lacc = (f32x4)0.f;

    int cur = 0;
    for (int kt = 0; kt < S_LEN; kt += 64, cur ^= 1) {
        // prefetch next K/V tile into the other buffer (drained by end barrier)
        if (kt + 64 < S_LEN) {
#pragma unroll
            for (int i = 0; i < 2; i++) {
                const int row0 = w * 16 + i * 8;
                gll16(kb + (size_t)(kt + 64 + row0 + srow) * 64 + sblk * 8,
                      &Ks[cur ^ 1][row0 * 64]);
                gll16(vb + (size_t)(row0 + srow) * S_LEN + kt + 64 + sblk * 8,
                      &Vs[cur ^ 1][row0 * 64]);
            }
        }
        const h16* Kc = Ks[cur];
        const h16* Vc = Vs[cur];

        // S^T = mfma(Kf, Qf): lane holds S^T[t=16tb+4g+r][s=16w+ln] (exp2 domain)
        f32x4 sacc[4];
#pragma unroll
        for (int tb = 0; tb < 4; tb++) sacc[tb] = (f32x4)0.f;
#pragma unroll
        for (int c = 0; c < 2; c++) {
            const int cq = (c * 64 + g * 16) ^ ((ln & 7) << 4);
            f16x8 qf = *(const f16x8*)&Qs[(16 * w + ln) * 64 + cq / 2];
#pragma unroll
            for (int tb = 0; tb < 4; tb++) {
                const int row = tb * 16 + ln;
                const int cb = (c * 64 + g * 16) ^ ((row & 7) << 4);
                f16x8 kf = *(const f16x8*)&Kc[row * 64 + cb / 2];
                sacc[tb] = __builtin_amdgcn_mfma_f32_16x16x32_f16(kf, qf, sacc[tb], 0, 0, 0);
            }
        }

        // column max (pairwise tree) + cross-group reduce
        float m0 = fmaxf(fmaxf(sacc[0][0], sacc[0][1]), fmaxf(sacc[0][2], sacc[0][3]));
        float m1 = fmaxf(fmaxf(sacc[1][0], sacc[1][1]), fmaxf(sacc[1][2], sacc[1][3]));
        float m2 = fmaxf(fmaxf(sacc[2][0], sacc[2][1]), fmaxf(sacc[2][2], sacc[2][3]));
        float m3 = fmaxf(fmaxf(sacc[3][0], sacc[3][1]), fmaxf(sacc[3][2], sacc[3][3]));
        float mloc = fmaxf(fmaxf(m0, m1), fmaxf(m2, m3));
        mloc = fmaxf(mloc, __shfl_xor(mloc, 16));
        mloc = fmaxf(mloc, __shfl_xor(mloc, 32));

        // defer-max: rescale only when tile max grew past threshold
        if (!__all(mloc <= m_run + 8.0f)) {
            const float mnew = fmaxf(m_run, mloc);
            const float resc = fexp2(m_run - mnew);
#pragma unroll
            for (int db = 0; db < 4; db++)
#pragma unroll
                for (int r = 0; r < 4; r++) oacc[db][r] *= resc;
#pragma unroll
            for (int r = 0; r < 4; r++) lacc[r] *= resc;
            m_run = mnew;
        }

        // P = exp2(S - m_run), pack rtz, write wave-private LDS rows
#pragma unroll
        for (int tb = 0; tb < 4; tb++) {
            union { fp16x2r v[2]; uint2 u; } pk;
            pk.v[0] = __builtin_amdgcn_cvt_pkrtz(fexp2(sacc[tb][0] - m_run),
                                                 fexp2(sacc[tb][1] - m_run));
            pk.v[1] = __builtin_amdgcn_cvt_pkrtz(fexp2(sacc[tb][2] - m_run),
                                                 fexp2(sacc[tb][3] - m_run));
            const int cb = (tb * 32 + g * 8) ^ ((ln & 7) << 4);
            *(uint2*)&Ps[(16 * w + ln) * 64 + cb / 2] = pk.u;
        }

        // O += mfma(Vf, Pf); l += mfma(ones, Pf)
#pragma unroll
        for (int c = 0; c < 2; c++) {
            const int cp = (c * 64 + g * 16) ^ ((ln & 7) << 4);
            f16x8 pf = *(const f16x8*)&Ps[(16 * w + ln) * 64 + cp / 2];
            lacc = __builtin_amdgcn_mfma_f32_16x16x32_f16(ones, pf, lacc, 0, 0, 0);
#pragma unroll
            for (int db = 0; db < 4; db++) {
                const int row = db * 16 + ln;
                const int cb = (c * 64 + g * 16) ^ ((row & 7) << 4);
                f16x8 vf = *(const f16x8*)&Vc[row * 64 + cb / 2];
                oacc[db] = __builtin_amdgcn_mfma_f32_16x16x32_f16(vf, pf, oacc[db], 0, 0, 0);
            }
        }
        __syncthreads();   // next tile staged (vmcnt drain) + Ks/Vs reads done
    }

    // epilogue: attT[b][s0+16w+ln][h*64 + d], 8B chunks
    const float inv = 1.0f / lacc[0];
    h16* ob = attT + ((size_t)b * S_LEN + s0 + 16 * w + ln) * CDIM + h * 64;
#pragma unroll
    for (int db = 0; db < 4; db++) {
        union { h16 h[4]; uint2 u; } pk;
#pragma unroll
        for (int r = 0; r < 4; r++) pk.h[r] = (h16)(oacc[db][r] * inv);
        *(uint2*)(ob + db * 16 + 4 * g) = pk.u;
    }
}

// ---------------------------------------------------------------------------
// Kernel 3: output projection. A=attT[b][n][k], B=Wout_h[m][k].
// ---------------------------------------------------------------------------
__global__ __launch_bounds__(256) void gemm_out(
    const h16* __restrict__ attT, const h16* __restrict__ Wh,
    const float* __restrict__ bout, float* __restrict__ out)
{
    const int n0 = blockIdx.x * 128;
    const int m0 = blockIdx.y * 128;
    const int b  = blockIdx.z;
    __shared__ h16 Ws[128 * 64];
    __shared__ h16 Xs[128 * 64];

    const int tid = threadIdx.x;
    const int lid = tid & 63, w = tid >> 6;
    const int g = lid >> 4, ln = lid & 15;
    const int wm = w & 1, wn = w >> 1;
    const int srow = lid >> 3;
    const int sblk = (lid & 7) ^ (srow & 7);

    f32x4 acc[4][4];
#pragma unroll
    for (int i = 0; i < 4; i++)
#pragma unroll
        for (int j = 0; j < 4; j++) acc[i][j] = (f32x4)0.f;

    const h16* Wbase = Wh + (size_t)m0 * CDIM;
    const h16* Xbase = attT + ((size_t)b * S_LEN + n0) * CDIM;

    for (int kt = 0; kt < CDIM; kt += 64) {
        __syncthreads();
#pragma unroll
        for (int i = 0; i < 4; i++) {
            const int row0 = w * 32 + i * 8;
            gll16(Wbase + (size_t)(row0 + srow) * CDIM + kt + sblk * 8, &Ws[row0 * 64]);
            gll16(Xbase + (size_t)(row0 + srow) * CDIM + kt + sblk * 8, &Xs[row0 * 64]);
        }
        __syncthreads();

#pragma unroll
        for (int kc = 0; kc < 2; kc++) {
            f16x8 af[4], bf[4];
#pragma unroll
            for (int i = 0; i < 4; i++) {
                const int ra = wm * 64 + i * 16 + ln;
                const int ca = (kc * 64 + g * 16) ^ ((ra & 7) << 4);
                af[i] = *(const f16x8*)&Ws[ra * 64 + ca / 2];
                const int rb = wn * 64 + i * 16 + ln;
                const int cb = (kc * 64 + g * 16) ^ ((rb & 7) << 4);
                bf[i] = *(const f16x8*)&Xs[rb * 64 + cb / 2];
            }
#pragma unroll
            for (int i = 0; i < 4; i++)
#pragma unroll
                for (int j = 0; j < 4; j++)
                    acc[i][j] = __builtin_amdgcn_mfma_f32_16x16x32_f16(
                        bf[i], af[j], acc[i][j], 0, 0, 0);
        }
    }

#pragma unroll
    for (int j = 0; j < 4; j++) {
        const int m = m0 + wm * 64 + j * 16 + ln;
        const float bias = bout[m];
        float* base = out + ((size_t)b * CDIM + m) * S_LEN;
#pragma unroll
        for (int i = 0; i < 4; i++) {
            const int nb = n0 + wn * 64 + i * 16 + 4 * g;
            float4 o;
            o.x = acc[i][j][0] + bias;
            o.y = acc[i][j][1] + bias;
            o.z = acc[i][j][2] + bias;
            o.w = acc[i][j][3] + bias;
            *(float4*)(base + nb) = o;
        }
    }
}

// ---------------------------------------------------------------------------
extern "C" void kernel_launch(void* const* d_in, const int* in_sizes, int n_in,
                              void* d_out, int out_size, void* d_ws, size_t ws_size,
                              hipStream_t stream)
{
    const float* x    = (const float*)d_in[0];
    const float* Wqkv = (const float*)d_in[1];
    const float* bqkv = (const float*)d_in[2];
    const float* Wout = (const float*)d_in[3];
    const float* bout = (const float*)d_in[4];
    float* out = (float*)d_out;

    h16* xT   = (h16*)d_ws;                          // [4][2304][512]
    h16* Wq_h = xT   + (size_t)4 * S_LEN * CDIM;     // [1536][512]
    h16* Wo_h = Wq_h + (size_t)1536 * 512;           // [512][512]
    h16* qT   = Wo_h + (size_t)512 * 512;            // [4][8][2304][64]
    h16* kT   = qT   + (size_t)4 * 8 * S_LEN * 64;
    h16* vN   = kT   + (size_t)4 * 8 * S_LEN * 64;   // [4][8][64][2304]
    h16* attT = vN   + (size_t)4 * 8 * S_LEN * 64;   // [4][2304][512]

    xpose_x <<<dim3(36, 8, 4),  256, 0, stream>>>(x, xT);
    wconv   <<<1024,            256, 0, stream>>>(Wqkv, Wout, Wq_h, Wo_h);
    gemm_qkv<<<dim3(18, 12, 4), 256, 0, stream>>>(Wq_h, bqkv, xT, qT, kT, vN);
    attn_f16<<<dim3(36, 8, 4),  256, 0, stream>>>(qT, kT, vN, attT);
    gemm_out<<<dim3(18, 4, 4),  256, 0, stream>>>(attT, Wo_h, bout, out);
}

// Round 7
// 151.307 us; speedup vs baseline: 6.7476x; 1.0340x over previous
//
#include <hip/hip_runtime.h>

#define S_LEN 2304   // 48*48
#define CDIM  512
#define NHEAD 8

typedef __attribute__((ext_vector_type(4))) float f32x4;
typedef __attribute__((ext_vector_type(8))) _Float16 f16x8;
typedef __attribute__((ext_vector_type(2))) __fp16 fp16x2r;  // cvt_pkrtz native type
typedef _Float16 h16;

// softmax runs in exp2 domain: q pre-scaled by 1/sqrt(64) * log2(e)
#define QSCALE 0.18033688011112042f

__device__ __forceinline__ float fexp2(float x) {
#if __has_builtin(__builtin_amdgcn_exp2f)
    return __builtin_amdgcn_exp2f(x);
#else
    return exp2f(x);
#endif
}

// async global->LDS, 16B per lane; LDS dest = wave-uniform base + lane*16
__device__ __forceinline__ void gll16(const h16* g, h16* l) {
    __builtin_amdgcn_global_load_lds(
        (const __attribute__((address_space(1))) unsigned int*)g,
        (__attribute__((address_space(3))) unsigned int*)l, 16, 0, 0);
}

// ---------------------------------------------------------------------------
// Kernel 0a: transpose+convert x[b][c][s] fp32 -> xT[b][s][c] fp16
// ---------------------------------------------------------------------------
__global__ __launch_bounds__(256) void xpose_x(
    const float* __restrict__ x, h16* __restrict__ xT)
{
    const int s0 = blockIdx.x * 64;
    const int c0 = blockIdx.y * 64;
    const int b  = blockIdx.z;
    __shared__ h16 Ts[64][76];

    const int t  = threadIdx.x;
    const int cq = t >> 4;
    const int sq = t & 15;

    const float* xb = x + ((size_t)b * CDIM + c0 + cq * 4) * S_LEN + s0 + sq * 4;
    float4 r0 = *(const float4*)(xb);
    float4 r1 = *(const float4*)(xb + S_LEN);
    float4 r2 = *(const float4*)(xb + 2 * S_LEN);
    float4 r3 = *(const float4*)(xb + 3 * S_LEN);

    union { h16 h[4]; uint2 u; } pk;
    pk.h[0]=(h16)r0.x; pk.h[1]=(h16)r1.x; pk.h[2]=(h16)r2.x; pk.h[3]=(h16)r3.x;
    *(uint2*)&Ts[sq*4+0][cq*4] = pk.u;
    pk.h[0]=(h16)r0.y; pk.h[1]=(h16)r1.y; pk.h[2]=(h16)r2.y; pk.h[3]=(h16)r3.y;
    *(uint2*)&Ts[sq*4+1][cq*4] = pk.u;
    pk.h[0]=(h16)r0.z; pk.h[1]=(h16)r1.z; pk.h[2]=(h16)r2.z; pk.h[3]=(h16)r3.z;
    *(uint2*)&Ts[sq*4+2][cq*4] = pk.u;
    pk.h[0]=(h16)r0.w; pk.h[1]=(h16)r1.w; pk.h[2]=(h16)r2.w; pk.h[3]=(h16)r3.w;
    *(uint2*)&Ts[sq*4+3][cq*4] = pk.u;

    __syncthreads();
    const int s  = t >> 2;
    const int cc = (t & 3) * 16;
    uint2 a0 = *(uint2*)&Ts[s][cc + 0];
    uint2 a1 = *(uint2*)&Ts[s][cc + 4];
    uint2 a2 = *(uint2*)&Ts[s][cc + 8];
    uint2 a3 = *(uint2*)&Ts[s][cc + 12];
    h16* dst = xT + ((size_t)b * S_LEN + s0 + s) * CDIM + c0 + cc;
    uint4 w0 = make_uint4(a0.x, a0.y, a1.x, a1.y);
    uint4 w1 = make_uint4(a2.x, a2.y, a3.x, a3.y);
    *(uint4*)dst       = w0;
    *(uint4*)(dst + 8) = w1;
}

// ---------------------------------------------------------------------------
// Kernel 0b: convert Wqkv (1536x512) and Wout (512x512) fp32 -> fp16
// ---------------------------------------------------------------------------
__global__ __launch_bounds__(256) void wconv(
    const float* __restrict__ Wq, const float* __restrict__ Wo,
    h16* __restrict__ Wq_h, h16* __restrict__ Wo_h)
{
    const int NQ = 1536 * 512;
    const int NO = 512 * 512;
    int i = (blockIdx.x * 256 + threadIdx.x) * 4;
    if (i >= NQ + NO) return;
    float4 v;
    h16* dst;
    if (i < NQ) { v = *(const float4*)(Wq + i);        dst = Wq_h + i; }
    else        { v = *(const float4*)(Wo + (i - NQ)); dst = Wo_h + (i - NQ); }
    union { h16 h[4]; uint2 u; } pk;
    pk.h[0]=(h16)v.x; pk.h[1]=(h16)v.y; pk.h[2]=(h16)v.z; pk.h[3]=(h16)v.w;
    *(uint2*)dst = pk.u;
}

// ---------------------------------------------------------------------------
// Kernel 1: QKV projection, fp16 MFMA. q rows get *QSCALE (softmax exp2 domain).
// ---------------------------------------------------------------------------
__global__ __launch_bounds__(256) void gemm_qkv(
    const h16* __restrict__ Wh, const float* __restrict__ bqkv,
    const h16* __restrict__ xT, h16* __restrict__ qT, h16* __restrict__ kT,
    h16* __restrict__ vN)
{
    const int n0 = blockIdx.x * 128;
    const int m0 = blockIdx.y * 128;
    const int b  = blockIdx.z;
    __shared__ h16 Ws[128 * 64];
    __shared__ h16 Xs[128 * 64];

    const int tid = threadIdx.x;
    const int lid = tid & 63, w = tid >> 6;
    const int g = lid >> 4, ln = lid & 15;
    const int wm = w & 1, wn = w >> 1;
    const int srow = lid >> 3;
    const int sblk = (lid & 7) ^ (srow & 7);

    f32x4 acc[4][4];
#pragma unroll
    for (int i = 0; i < 4; i++)
#pragma unroll
        for (int j = 0; j < 4; j++) acc[i][j] = (f32x4)0.f;

    const h16* Wbase = Wh + (size_t)m0 * CDIM;
    const h16* Xbase = xT + ((size_t)b * S_LEN + n0) * CDIM;
    const bool vblk = (m0 >= 1024);

    for (int kt = 0; kt < CDIM; kt += 64) {
        __syncthreads();
#pragma unroll
        for (int i = 0; i < 4; i++) {
            const int row0 = w * 32 + i * 8;
            gll16(Wbase + (size_t)(row0 + srow) * CDIM + kt + sblk * 8, &Ws[row0 * 64]);
            gll16(Xbase + (size_t)(row0 + srow) * CDIM + kt + sblk * 8, &Xs[row0 * 64]);
        }
        __syncthreads();

#pragma unroll
        for (int kc = 0; kc < 2; kc++) {
            f16x8 af[4], bf[4];
#pragma unroll
            for (int i = 0; i < 4; i++) {
                const int ra = wm * 64 + i * 16 + ln;
                const int ca = (kc * 64 + g * 16) ^ ((ra & 7) << 4);
                af[i] = *(const f16x8*)&Ws[ra * 64 + ca / 2];
                const int rb = wn * 64 + i * 16 + ln;
                const int cb = (kc * 64 + g * 16) ^ ((rb & 7) << 4);
                bf[i] = *(const f16x8*)&Xs[rb * 64 + cb / 2];
            }
            if (!vblk) {
#pragma unroll
                for (int i = 0; i < 4; i++)
#pragma unroll
                    for (int j = 0; j < 4; j++)
                        acc[i][j] = __builtin_amdgcn_mfma_f32_16x16x32_f16(
                            af[i], bf[j], acc[i][j], 0, 0, 0);
            } else {
#pragma unroll
                for (int i = 0; i < 4; i++)
#pragma unroll
                    for (int j = 0; j < 4; j++)
                        acc[i][j] = __builtin_amdgcn_mfma_f32_16x16x32_f16(
                            bf[i], af[j], acc[i][j], 0, 0, 0);
            }
        }
    }

    if (!vblk) {
#pragma unroll
        for (int i = 0; i < 4; i++) {
            const int mb = m0 + wm * 64 + i * 16 + 4 * g;
            const float4 bv = *(const float4*)&bqkv[mb];
            const int mloc = mb & 511;
            const int hh = mloc >> 6, d0 = mloc & 63;
            const bool isq = (mb < 512);
            const float scl = isq ? QSCALE : 1.0f;
            h16* base = (isq ? qT : kT);
#pragma unroll
            for (int j = 0; j < 4; j++) {
                const int n = n0 + wn * 64 + j * 16 + ln;
                union { h16 h[4]; uint2 u; } pk;
                pk.h[0] = (h16)((acc[i][j][0] + bv.x) * scl);
                pk.h[1] = (h16)((acc[i][j][1] + bv.y) * scl);
                pk.h[2] = (h16)((acc[i][j][2] + bv.z) * scl);
                pk.h[3] = (h16)((acc[i][j][3] + bv.w) * scl);
                *(uint2*)(base + (((size_t)b * 8 + hh) * S_LEN + n) * 64 + d0) = pk.u;
            }
        }
    } else {
#pragma unroll
        for (int j = 0; j < 4; j++) {
            const int m = m0 + wm * 64 + j * 16 + ln;
            const float bias = bqkv[m];
            const int mloc = m - 1024;
            const int hh = mloc >> 6, d = mloc & 63;
            h16* base = vN + (((size_t)b * 8 + hh) * 64 + d) * S_LEN;
#pragma unroll
            for (int i = 0; i < 4; i++) {
                const int nb = n0 + wn * 64 + i * 16 + 4 * g;
                union { h16 h[4]; uint2 u; } pk;
                pk.h[0] = (h16)(acc[i][j][0] + bias);
                pk.h[1] = (h16)(acc[i][j][1] + bias);
                pk.h[2] = (h16)(acc[i][j][2] + bias);
                pk.h[3] = (h16)(acc[i][j][3] + bias);
                *(uint2*)(base + nb) = pk.u;
            }
        }
    }
}

// ---------------------------------------------------------------------------
// Kernel 2: flash attention fp16, exp2-domain softmax.
//  - Q in REGISTERS (no Qs LDS): lane (ln,g) holds Q[s0+16w+ln][c*32+g*8..+7]
//  - LDS 40KB (K/V dbuf + P) -> 4 blocks/CU, __launch_bounds__(256,4)
//  - defer-max, ones-MFMA l-sum, double-buffered K/V staging
// ---------------------------------------------------------------------------
__global__ __launch_bounds__(256, 4) void attn_f16(
    const h16* __restrict__ qT, const h16* __restrict__ kT,
    const h16* __restrict__ vN, h16* __restrict__ attT)
{
    const int s0 = blockIdx.x * 64;
    const int h  = blockIdx.y;
    const int b  = blockIdx.z;
    __shared__ h16 Ks[2][64 * 64];
    __shared__ h16 Vs[2][64 * 64];
    __shared__ h16 Ps[64 * 64];

    const int tid = threadIdx.x;
    const int lid = tid & 63, w = tid >> 6;
    const int g = lid >> 4, ln = lid & 15;
    const int srow = lid >> 3;
    const int sblk = (lid & 7) ^ (srow & 7);

    const h16* qb = qT + ((size_t)b * 8 + h) * S_LEN * 64;
    const h16* kb = kT + ((size_t)b * 8 + h) * S_LEN * 64;
    const h16* vb = vN + ((size_t)b * 8 + h) * 64 * S_LEN;

    // Q straight to registers (global layout is linear; swizzle is LDS-only)
    f16x8 qreg[2];
    {
        const h16* qrow = qb + (size_t)(s0 + 16 * w + ln) * 64;
        qreg[0] = *(const f16x8*)(qrow + g * 8);
        qreg[1] = *(const f16x8*)(qrow + 32 + g * 8);
    }

    // prologue: stage tile 0 of K/V
#pragma unroll
    for (int i = 0; i < 2; i++) {
        const int row0 = w * 16 + i * 8;
        gll16(kb + (size_t)(row0 + srow) * 64 + sblk * 8, &Ks[0][row0 * 64]);
        gll16(vb + (size_t)(row0 + srow) * S_LEN + sblk * 8, &Vs[0][row0 * 64]);
    }
    __syncthreads();

    f16x8 ones;
#pragma unroll
    for (int i = 0; i < 8; i++) ones[i] = (h16)1.0f;

    float m_run = -1e30f;
    f32x4 oacc[4], lacc;
#pragma unroll
    for (int i = 0; i < 4; i++) oacc[i] = (f32x4)0.f;
    lacc = (f32x4)0.f;

    int cur = 0;
    for (int kt = 0; kt < S_LEN; kt += 64, cur ^= 1) {
        // prefetch next K/V tile into the other buffer (drained by end barrier)
        if (kt + 64 < S_LEN) {
#pragma unroll
            for (int i = 0; i < 2; i++) {
                const int row0 = w * 16 + i * 8;
                gll16(kb + (size_t)(kt + 64 + row0 + srow) * 64 + sblk * 8,
                      &Ks[cur ^ 1][row0 * 64]);
                gll16(vb + (size_t)(row0 + srow) * S_LEN + kt + 64 + sblk * 8,
                      &Vs[cur ^ 1][row0 * 64]);
            }
        }
        const h16* Kc = Ks[cur];
        const h16* Vc = Vs[cur];

        // S^T = mfma(Kf, Qf): lane holds S^T[t=16tb+4g+r][s=16w+ln] (exp2 domain)
        f32x4 sacc[4];
#pragma unroll
        for (int tb = 0; tb < 4; tb++) sacc[tb] = (f32x4)0.f;
#pragma unroll
        for (int c = 0; c < 2; c++) {
#pragma unroll
            for (int tb = 0; tb < 4; tb++) {
                const int row = tb * 16 + ln;
                const int cb = (c * 64 + g * 16) ^ ((row & 7) << 4);
                f16x8 kf = *(const f16x8*)&Kc[row * 64 + cb / 2];
                sacc[tb] = __builtin_amdgcn_mfma_f32_16x16x32_f16(kf, qreg[c], sacc[tb], 0, 0, 0);
            }
        }

        // column max (pairwise tree) + cross-group reduce
        float m0 = fmaxf(fmaxf(sacc[0][0], sacc[0][1]), fmaxf(sacc[0][2], sacc[0][3]));
        float m1 = fmaxf(fmaxf(sacc[1][0], sacc[1][1]), fmaxf(sacc[1][2], sacc[1][3]));
        float m2 = fmaxf(fmaxf(sacc[2][0], sacc[2][1]), fmaxf(sacc[2][2], sacc[2][3]));
        float m3 = fmaxf(fmaxf(sacc[3][0], sacc[3][1]), fmaxf(sacc[3][2], sacc[3][3]));
        float mloc = fmaxf(fmaxf(m0, m1), fmaxf(m2, m3));
        mloc = fmaxf(mloc, __shfl_xor(mloc, 16));
        mloc = fmaxf(mloc, __shfl_xor(mloc, 32));

        // defer-max: rescale only when tile max grew past threshold
        if (!__all(mloc <= m_run + 8.0f)) {
            const float mnew = fmaxf(m_run, mloc);
            const float resc = fexp2(m_run - mnew);
#pragma unroll
            for (int db = 0; db < 4; db++)
#pragma unroll
                for (int r = 0; r < 4; r++) oacc[db][r] *= resc;
#pragma unroll
            for (int r = 0; r < 4; r++) lacc[r] *= resc;
            m_run = mnew;
        }

        // P = exp2(S - m_run), pack rtz, write wave-private LDS rows
#pragma unroll
        for (int tb = 0; tb < 4; tb++) {
            union { fp16x2r v[2]; uint2 u; } pk;
            pk.v[0] = __builtin_amdgcn_cvt_pkrtz(fexp2(sacc[tb][0] - m_run),
                                                 fexp2(sacc[tb][1] - m_run));
            pk.v[1] = __builtin_amdgcn_cvt_pkrtz(fexp2(sacc[tb][2] - m_run),
                                                 fexp2(sacc[tb][3] - m_run));
            const int cb = (tb * 32 + g * 8) ^ ((ln & 7) << 4);
            *(uint2*)&Ps[(16 * w + ln) * 64 + cb / 2] = pk.u;
        }

        // O += mfma(Vf, Pf); l += mfma(ones, Pf)
#pragma unroll
        for (int c = 0; c < 2; c++) {
            const int cp = (c * 64 + g * 16) ^ ((ln & 7) << 4);
            f16x8 pf = *(const f16x8*)&Ps[(16 * w + ln) * 64 + cp / 2];
            lacc = __builtin_amdgcn_mfma_f32_16x16x32_f16(ones, pf, lacc, 0, 0, 0);
#pragma unroll
            for (int db = 0; db < 4; db++) {
                const int row = db * 16 + ln;
                const int cb = (c * 64 + g * 16) ^ ((row & 7) << 4);
                f16x8 vf = *(const f16x8*)&Vc[row * 64 + cb / 2];
                oacc[db] = __builtin_amdgcn_mfma_f32_16x16x32_f16(vf, pf, oacc[db], 0, 0, 0);
            }
        }
        __syncthreads();   // next tile staged (vmcnt drain) + Ks/Vs reads done
    }

    // epilogue: attT[b][s0+16w+ln][h*64 + d], 8B chunks
    const float inv = 1.0f / lacc[0];
    h16* ob = attT + ((size_t)b * S_LEN + s0 + 16 * w + ln) * CDIM + h * 64;
#pragma unroll
    for (int db = 0; db < 4; db++) {
        union { h16 h[4]; uint2 u; } pk;
#pragma unroll
        for (int r = 0; r < 4; r++) pk.h[r] = (h16)(oacc[db][r] * inv);
        *(uint2*)(ob + db * 16 + 4 * g) = pk.u;
    }
}

// ---------------------------------------------------------------------------
// Kernel 3: output projection. A=attT[b][n][k], B=Wout_h[m][k].
// ---------------------------------------------------------------------------
__global__ __launch_bounds__(256) void gemm_out(
    const h16* __restrict__ attT, const h16* __restrict__ Wh,
    const float* __restrict__ bout, float* __restrict__ out)
{
    const int n0 = blockIdx.x * 128;
    const int m0 = blockIdx.y * 128;
    const int b  = blockIdx.z;
    __shared__ h16 Ws[128 * 64];
    __shared__ h16 Xs[128 * 64];

    const int tid = threadIdx.x;
    const int lid = tid & 63, w = tid >> 6;
    const int g = lid >> 4, ln = lid & 15;
    const int wm = w & 1, wn = w >> 1;
    const int srow = lid >> 3;
    const int sblk = (lid & 7) ^ (srow & 7);

    f32x4 acc[4][4];
#pragma unroll
    for (int i = 0; i < 4; i++)
#pragma unroll
        for (int j = 0; j < 4; j++) acc[i][j] = (f32x4)0.f;

    const h16* Wbase = Wh + (size_t)m0 * CDIM;
    const h16* Xbase = attT + ((size_t)b * S_LEN + n0) * CDIM;

    for (int kt = 0; kt < CDIM; kt += 64) {
        __syncthreads();
#pragma unroll
        for (int i = 0; i < 4; i++) {
            const int row0 = w * 32 + i * 8;
            gll16(Wbase + (size_t)(row0 + srow) * CDIM + kt + sblk * 8, &Ws[row0 * 64]);
            gll16(Xbase + (size_t)(row0 + srow) * CDIM + kt + sblk * 8, &Xs[row0 * 64]);
        }
        __syncthreads();

#pragma unroll
        for (int kc = 0; kc < 2; kc++) {
            f16x8 af[4], bf[4];
#pragma unroll
            for (int i = 0; i < 4; i++) {
                const int ra = wm * 64 + i * 16 + ln;
                const int ca = (kc * 64 + g * 16) ^ ((ra & 7) << 4);
                af[i] = *(const f16x8*)&Ws[ra * 64 + ca / 2];
                const int rb = wn * 64 + i * 16 + ln;
                const int cb = (kc * 64 + g * 16) ^ ((rb & 7) << 4);
                bf[i] = *(const f16x8*)&Xs[rb * 64 + cb / 2];
            }
#pragma unroll
            for (int i = 0; i < 4; i++)
#pragma unroll
                for (int j = 0; j < 4; j++)
                    acc[i][j] = __builtin_amdgcn_mfma_f32_16x16x32_f16(
                        bf[i], af[j], acc[i][j], 0, 0, 0);
        }
    }

#pragma unroll
    for (int j = 0; j < 4; j++) {
        const int m = m0 + wm * 64 + j * 16 + ln;
        const float bias = bout[m];
        float* base = out + ((size_t)b * CDIM + m) * S_LEN;
#pragma unroll
        for (int i = 0; i < 4; i++) {
            const int nb = n0 + wn * 64 + i * 16 + 4 * g;
            float4 o;
            o.x = acc[i][j][0] + bias;
            o.y = acc[i][j][1] + bias;
            o.z = acc[i][j][2] + bias;
            o.w = acc[i][j][3] + bias;
            *(float4*)(base + nb) = o;
        }
    }
}

// ---------------------------------------------------------------------------
extern "C" void kernel_launch(void* const* d_in, const int* in_sizes, int n_in,
                              void* d_out, int out_size, void* d_ws, size_t ws_size,
                              hipStream_t stream)
{
    const float* x    = (const float*)d_in[0];
    const float* Wqkv = (const float*)d_in[1];
    const float* bqkv = (const float*)d_in[2];
    const float* Wout = (const float*)d_in[3];
    const float* bout = (const float*)d_in[4];
    float* out = (float*)d_out;

    h16* xT   = (h16*)d_ws;                          // [4][2304][512]
    h16* Wq_h = xT   + (size_t)4 * S_LEN * CDIM;     // [1536][512]
    h16* Wo_h = Wq_h + (size_t)1536 * 512;           // [512][512]
    h16* qT   = Wo_h + (size_t)512 * 512;            // [4][8][2304][64]
    h16* kT   = qT   + (size_t)4 * 8 * S_LEN * 64;
    h16* vN   = kT   + (size_t)4 * 8 * S_LEN * 64;   // [4][8][64][2304]
    h16* attT = vN   + (size_t)4 * 8 * S_LEN * 64;   // [4][2304][512]

    xpose_x <<<dim3(36, 8, 4),  256, 0, stream>>>(x, xT);
    wconv   <<<1024,            256, 0, stream>>>(Wqkv, Wout, Wq_h, Wo_h);
    gemm_qkv<<<dim3(18, 12, 4), 256, 0, stream>>>(Wq_h, bqkv, xT, qT, kT, vN);
    attn_f16<<<dim3(36, 8, 4),  256, 0, stream>>>(qT, kT, vN, attT);
    gemm_out<<<dim3(18, 4, 4),  256, 0, stream>>>(attT, Wo_h, bout, out);
}